// Round 15
// baseline (211.337 us; speedup 1.0000x reference)
//
#include <hip/hip_runtime.h>

#define NODES   50000
#define EDGES   1200000
#define IND     256
#define HID     64
#define BN_EPS  1e-5f
#define BSHIFT  6
#define BNODES  64
#define NBUCK   782                 // ceil(50000/64)
#define EPB     2048
#define BIN_BLOCKS 586              // x 2048 = 1,200,128 >= EDGES
#define BSTRIDE 2560                // bucket capacity (mean 1536, +26 sigma)
#define DMAX    64                  // per-node CSR slots (max in-deg Poisson(24) ~ 55)
#define GBLK    782                 // gemm1: 64 nodes per block

// ---------------------------------------------------------------- init
__global__ __launch_bounds__(1024) void k_init(int* cursor, float* bnsum, float* bnsq) {
    int t = threadIdx.x;
    if (t < NBUCK) cursor[t] = 0;
    if (t < HID) { bnsum[t] = 0.f; bnsq[t] = 0.f; }
}

// ---------------------------------------------------------------- bin edges by dst bucket (fixed-stride buckets)
__global__ __launch_bounds__(256) void k_bin(const int* __restrict__ src, const int* __restrict__ dst,
                                             int* cursor, unsigned int* __restrict__ pair_buf) {
    __shared__ int hist[NBUCK];
    __shared__ int base[NBUCK];
    __shared__ int cur[NBUCK];
    int t = threadIdx.x;
    int e0 = blockIdx.x * EPB;
    for (int j = t; j < NBUCK; j += 256) { hist[j] = 0; cur[j] = 0; }
    __syncthreads();
    int d[8];
#pragma unroll
    for (int i = 0; i < 8; ++i) {
        int e = e0 + t + i * 256;
        d[i] = (e < EDGES) ? dst[e] : -1;
        if (d[i] >= 0) atomicAdd(&hist[d[i] >> BSHIFT], 1);
    }
    __syncthreads();
    for (int j = t; j < NBUCK; j += 256) {
        int h = hist[j];
        base[j] = h ? atomicAdd(&cursor[j], h) : 0;
    }
    __syncthreads();
#pragma unroll
    for (int i = 0; i < 8; ++i) {
        int e = e0 + t + i * 256;
        if (d[i] >= 0) {
            int b = d[i] >> BSHIFT;
            int rel = base[b] + atomicAdd(&cur[b], 1);
            if (rel < BSTRIDE)
                pair_buf[b * BSTRIDE + rel] = (unsigned)src[e] | ((unsigned)(d[i] & (BNODES - 1)) << 16);
        }
    }
}

// ---------------------------------------------------------------- per-bucket scatter -> node-strided CSR + deg + dinv
__global__ __launch_bounds__(256) void k_csr(const int* __restrict__ cursor, const unsigned* __restrict__ pair_buf,
                                             unsigned short* __restrict__ csr, unsigned char* __restrict__ deg8,
                                             float* __restrict__ dinv) {
    __shared__ int cur[BNODES];
    int t = threadIdx.x, b = blockIdx.x;
    if (t < BNODES) cur[t] = 0;
    __syncthreads();
    int m = cursor[b]; if (m > BSTRIDE) m = BSTRIDE;
    const unsigned* pb = pair_buf + b * BSTRIDE;
    for (int i = t; i < m; i += 256) {
        unsigned p = pb[i];
        int node = p >> 16;
        int pos = atomicAdd(&cur[node], 1);
        if (pos < DMAX)
            csr[(((b << BSHIFT) + node) << 6) + pos] = (unsigned short)(p & 0xFFFFu);
    }
    __syncthreads();
    if (t < BNODES) {
        int n = (b << BSHIFT) + t;
        if (n < NODES) {
            int c = cur[t]; if (c > DMAX) c = DMAX;
            deg8[n] = (unsigned char)c;
            dinv[n] = rsqrtf((float)(c + 1));   // + self-loop
        }
    }
}

// ---------------------------------------------------------------- GEMM1: g = (x @ W1) * dinv
// NO LDS, no barriers. lane = output column (64), wave owns 16 nodes.
// W[k][lane]: coalesced vector loads -> wreg[64] per 64-k chunk (reused x16 nodes).
// x[n][k]: wave-uniform address (readfirstlane'd node) -> scalar s_load pipe.
// Inner: 4 independent node chains x 64 FMAs -> VALU-bound, straight-line code.
__global__ __launch_bounds__(256) void k_gemm1(const float* __restrict__ x, const float* __restrict__ W1,
                                               const float* __restrict__ dinv, float* __restrict__ g) {
    int t = threadIdx.x;
    int lane = t & 63;                    // output column
    int w = t >> 6;                       // wave -> node quarter
    int nbase = __builtin_amdgcn_readfirstlane(blockIdx.x * 64 + w * 16);

    float acc[16];
#pragma unroll
    for (int i = 0; i < 16; ++i) acc[i] = 0.f;

    for (int kc = 0; kc < IND; kc += 64) {
        float wreg[64];
#pragma unroll
        for (int k = 0; k < 64; ++k)
            wreg[k] = W1[(long)(kc + k) * HID + lane];   // 256B coalesced per k

#pragma unroll
        for (int ng = 0; ng < 4; ++ng) {
            int r0 = nbase + ng * 4;
            int m0 = (r0 + 0 < NODES) ? r0 + 0 : NODES - 1;
            int m1 = (r0 + 1 < NODES) ? r0 + 1 : NODES - 1;
            int m2 = (r0 + 2 < NODES) ? r0 + 2 : NODES - 1;
            int m3 = (r0 + 3 < NODES) ? r0 + 3 : NODES - 1;
            const float4* p0 = (const float4*)(x + (long)m0 * IND + kc);
            const float4* p1 = (const float4*)(x + (long)m1 * IND + kc);
            const float4* p2 = (const float4*)(x + (long)m2 * IND + kc);
            const float4* p3 = (const float4*)(x + (long)m3 * IND + kc);
            float a0 = acc[ng * 4 + 0], a1 = acc[ng * 4 + 1];
            float a2 = acc[ng * 4 + 2], a3 = acc[ng * 4 + 3];
#pragma unroll
            for (int k4 = 0; k4 < 16; ++k4) {
                float4 x0 = p0[k4];   // wave-uniform -> s_load_dwordx4
                float4 x1 = p1[k4];
                float4 x2 = p2[k4];
                float4 x3 = p3[k4];
#pragma unroll
                for (int kk = 0; kk < 4; ++kk) {
                    float wv = wreg[k4 * 4 + kk];
                    a0 = fmaf(((const float*)&x0)[kk], wv, a0);
                    a1 = fmaf(((const float*)&x1)[kk], wv, a1);
                    a2 = fmaf(((const float*)&x2)[kk], wv, a2);
                    a3 = fmaf(((const float*)&x3)[kk], wv, a3);
                }
            }
            acc[ng * 4 + 0] = a0; acc[ng * 4 + 1] = a1;
            acc[ng * 4 + 2] = a2; acc[ng * 4 + 3] = a3;
        }
    }

#pragma unroll
    for (int i = 0; i < 16; ++i) {
        int n = nbase + i;
        if (n < NODES) g[(long)n * HID + lane] = acc[i] * dinv[n];
    }
}

// ---------------------------------------------------------------- conv1 gather: wave per node, 16 edges in flight
__global__ __launch_bounds__(256) void k_gather1(const unsigned short* __restrict__ csr,
                                                 const unsigned char* __restrict__ deg8,
                                                 const float* __restrict__ g, const float* __restrict__ dinv,
                                                 const float* __restrict__ b1, float* __restrict__ h1) {
    int n = (blockIdx.x * 256 + threadIdx.x) >> 6;
    int lane = threadIdx.x & 63;
    if (n >= NODES) return;
    int sub = lane >> 3;
    int c8  = lane & 7;
    const float4* g4 = (const float4*)g;
    float4 a0 = { 0.f, 0.f, 0.f, 0.f }, a1 = { 0.f, 0.f, 0.f, 0.f };
    if (sub == 0) {                               // self-loop term, once
        a0 = g4[n * 16 + c8 * 2];
        a1 = g4[n * 16 + c8 * 2 + 1];
    }
    int cnt = deg8[n];
    const unsigned short* lst = csr + ((long)n << 6);
    int e = sub;
    for (; e + 8 < cnt; e += 16) {               // both e and e+8 valid for every sub
        int sA = lst[e];
        int sB = lst[e + 8];
        float4 vA0 = g4[sA * 16 + c8 * 2];
        float4 vA1 = g4[sA * 16 + c8 * 2 + 1];
        float4 vB0 = g4[sB * 16 + c8 * 2];
        float4 vB1 = g4[sB * 16 + c8 * 2 + 1];
        a0.x += vA0.x + vB0.x; a0.y += vA0.y + vB0.y;
        a0.z += vA0.z + vB0.z; a0.w += vA0.w + vB0.w;
        a1.x += vA1.x + vB1.x; a1.y += vA1.y + vB1.y;
        a1.z += vA1.z + vB1.z; a1.w += vA1.w + vB1.w;
    }
    for (; e < cnt; e += 8) {
        int s = lst[e];
        float4 v0 = g4[s * 16 + c8 * 2];
        float4 v1 = g4[s * 16 + c8 * 2 + 1];
        a0.x += v0.x; a0.y += v0.y; a0.z += v0.z; a0.w += v0.w;
        a1.x += v1.x; a1.y += v1.y; a1.z += v1.z; a1.w += v1.w;
    }
#pragma unroll
    for (int off = 8; off <= 32; off <<= 1) {
        a0.x += __shfl_xor(a0.x, off);
        a0.y += __shfl_xor(a0.y, off);
        a0.z += __shfl_xor(a0.z, off);
        a0.w += __shfl_xor(a0.w, off);
        a1.x += __shfl_xor(a1.x, off);
        a1.y += __shfl_xor(a1.y, off);
        a1.z += __shfl_xor(a1.z, off);
        a1.w += __shfl_xor(a1.w, off);
    }
    if (sub == 0) {
        float di = dinv[n];
        float4 bb0 = ((const float4*)b1)[c8 * 2];
        float4 bb1 = ((const float4*)b1)[c8 * 2 + 1];
        float4 o0, o1;
        o0.x = fmaf(a0.x, di, bb0.x); o0.y = fmaf(a0.y, di, bb0.y);
        o0.z = fmaf(a0.z, di, bb0.z); o0.w = fmaf(a0.w, di, bb0.w);
        o1.x = fmaf(a1.x, di, bb1.x); o1.y = fmaf(a1.y, di, bb1.y);
        o1.z = fmaf(a1.z, di, bb1.z); o1.w = fmaf(a1.w, di, bb1.w);
        ((float4*)h1)[n * 16 + c8 * 2] = o0;
        ((float4*)h1)[n * 16 + c8 * 2 + 1] = o1;
    }
}

// ---------------------------------------------------------------- BN stats over h1
__global__ __launch_bounds__(256) void k_bnstats(const float* __restrict__ h1, float* bnsum, float* bnsq) {
    __shared__ float sS[256], sQ[256];
    int t = threadIdx.x;
    int j = t & 63;
    int worker = (blockIdx.x * 256 + t) >> 6;
    int nworkers = (gridDim.x * 256) >> 6;
    float s = 0.f, q = 0.f;
    for (int n = worker; n < NODES; n += nworkers) {
        float v = h1[n * HID + j];
        s += v;
        q += v * v;
    }
    sS[t] = s; sQ[t] = q;
    __syncthreads();
    if (t < 64) {
        s = sS[t] + sS[t + 64] + sS[t + 128] + sS[t + 192];
        q = sQ[t] + sQ[t + 64] + sQ[t + 128] + sQ[t + 192];
        atomicAdd(&bnsum[t], s);
        atomicAdd(&bnsq[t], q);
    }
}

// ---------------------------------------------------------------- q = relu(bn(h1)) @ W2 * dinv  (bnfinal fused)
__global__ __launch_bounds__(256) void k_q(const float* __restrict__ h1, const float* __restrict__ bnsum,
                                           const float* __restrict__ bnsq, const float* __restrict__ gamma,
                                           const float* __restrict__ beta, const float* __restrict__ W2,
                                           const float* __restrict__ dinv, float* q) {
    int gt = blockIdx.x * 256 + threadIdx.x;
    int lane = threadIdx.x & 63;
    int n = gt >> 6;
    if (n >= NODES) return;
    float mean = bnsum[lane] * (1.f / NODES);
    float var  = bnsq[lane] * (1.f / NODES) - mean * mean;
    float sc = gamma[lane] * rsqrtf(var + BN_EPS);
    float sh = beta[lane] - mean * sc;
    float v = fmaxf(fmaf(h1[n * HID + lane], sc, sh), 0.f);
    float q0 = v * W2[lane * 2 + 0];
    float q1 = v * W2[lane * 2 + 1];
#pragma unroll
    for (int off = 32; off; off >>= 1) {
        q0 += __shfl_down(q0, off);
        q1 += __shfl_down(q1, off);
    }
    if (lane == 0) {
        float di = dinv[n];
        q[n * 2 + 0] = q0 * di;
        q[n * 2 + 1] = q1 * di;
    }
}

// ---------------------------------------------------------------- conv2 gather: 4 lanes per node
__global__ __launch_bounds__(256) void k_gather2(const unsigned short* __restrict__ csr,
                                                 const unsigned char* __restrict__ deg8,
                                                 const float* __restrict__ q, const float* __restrict__ dinv,
                                                 const float* __restrict__ b2, float* __restrict__ out) {
    int gt = blockIdx.x * 256 + threadIdx.x;
    int n = gt >> 2;
    int sub = gt & 3;
    if (n >= NODES) return;
    const float2* q2 = (const float2*)q;
    float q0 = 0.f, q1 = 0.f;
    if (sub == 0) { float2 s = q2[n]; q0 = s.x; q1 = s.y; }   // self-loop
    int cnt = deg8[n];
    const unsigned short* lst = csr + ((long)n << 6);
    for (int e = sub; e < cnt; e += 4) {
        float2 m = q2[lst[e]];
        q0 += m.x; q1 += m.y;
    }
    q0 += __shfl_xor(q0, 1); q1 += __shfl_xor(q1, 1);
    q0 += __shfl_xor(q0, 2); q1 += __shfl_xor(q1, 2);
    if (sub == 0) {
        float di = dinv[n];
        out[n * 2 + 0] = fmaf(q0, di, b2[0]);
        out[n * 2 + 1] = fmaf(q1, di, b2[1]);
    }
}

extern "C" void kernel_launch(void* const* d_in, const int* in_sizes, int n_in,
                              void* d_out, int out_size, void* d_ws, size_t ws_size,
                              hipStream_t stream) {
    const float* x     = (const float*)d_in[0];
    const int*   ei    = (const int*)d_in[1];
    const float* W1    = (const float*)d_in[2];
    const float* b1    = (const float*)d_in[3];
    const float* gamma = (const float*)d_in[4];
    const float* beta  = (const float*)d_in[5];
    const float* W2    = (const float*)d_in[6];
    const float* b2    = (const float*)d_in[7];
    const int* src = ei;
    const int* dst = ei + EDGES;
    float* out = (float*)d_out;

    float* f     = (float*)d_ws;
    float* dinv  = f;                                   // 50048 floats
    float* g     = dinv + 50048;                        // NODES*HID floats (12.8 MB)
    float* h1    = g + NODES * HID;                     // NODES*HID floats
    float* bnsum = h1 + NODES * HID;                    // 64
    float* bnsq  = bnsum + 64;                          // 64
    int*   cursor = (int*)(bnsq + 64);                  // 1024
    unsigned short* csr = (unsigned short*)(cursor + 1024);   // 50176*64 ushorts (6.4 MB)
    unsigned char* deg8 = (unsigned char*)(csr + 50176 * 64); // 50176 bytes
    unsigned* pair_buf = (unsigned*)g;                  // aliases g (NBUCK*BSTRIDE = 8 MB <= 12.8 MB)
    float* q = g;                                       // aliases g (dead after gather1)

    k_init <<<1, 1024, 0, stream>>>(cursor, bnsum, bnsq);
    k_bin  <<<BIN_BLOCKS, 256, 0, stream>>>(src, dst, cursor, pair_buf);
    k_csr  <<<NBUCK, 256, 0, stream>>>(cursor, pair_buf, csr, deg8, dinv);
    k_gemm1<<<GBLK, 256, 0, stream>>>(x, W1, dinv, g);
    k_gather1<<<(NODES * 64) / 256, 256, 0, stream>>>(csr, deg8, g, dinv, b1, h1);
    k_bnstats<<<256, 256, 0, stream>>>(h1, bnsum, bnsq);
    k_q<<<(NODES * 64) / 256, 256, 0, stream>>>(h1, bnsum, bnsq, gamma, beta, W2, dinv, q);
    k_gather2<<<(NODES * 4 + 255) / 256, 256, 0, stream>>>(csr, deg8, q, dinv, b2, out);
}

// Round 16
// 145.296 us; speedup vs baseline: 1.4545x; 1.4545x over previous
//
#include <hip/hip_runtime.h>
#include <hip/hip_bf16.h>

#define NODES   50000
#define EDGES   1200000
#define IND     256
#define HID     64
#define BN_EPS  1e-5f
#define BSHIFT  6
#define BNODES  64
#define NBUCK   782                 // ceil(50000/64)
#define EPB     2048
#define BIN_BLOCKS 586              // x 2048 = 1,200,128 >= EDGES
#define BSTRIDE 2560                // bucket capacity (mean 1536, +26 sigma)
#define DMAX    64                  // per-node CSR slots (max in-deg Poisson(24) ~ 55)
#define GBLK    782                 // gemm1: 64 nodes per block

static __device__ __forceinline__ unsigned f2bf2(float lo, float hi) {
    __hip_bfloat16 a = __float2bfloat16(lo);
    __hip_bfloat16 b = __float2bfloat16(hi);
    unsigned ua = *reinterpret_cast<unsigned short*>(&a);
    unsigned ub = *reinterpret_cast<unsigned short*>(&b);
    return ua | (ub << 16);
}
static __device__ __forceinline__ float bf_lo(unsigned u) {
    u <<= 16; return *reinterpret_cast<float*>(&u);
}
static __device__ __forceinline__ float bf_hi(unsigned u) {
    u &= 0xFFFF0000u; return *reinterpret_cast<float*>(&u);
}

// ---------------------------------------------------------------- init
__global__ __launch_bounds__(1024) void k_init(int* cursor, float* bnsum, float* bnsq) {
    int t = threadIdx.x;
    if (t < NBUCK) cursor[t] = 0;
    if (t < HID) { bnsum[t] = 0.f; bnsq[t] = 0.f; }
}

// ---------------------------------------------------------------- bin edges by dst bucket (fixed-stride buckets)
__global__ __launch_bounds__(256) void k_bin(const int* __restrict__ src, const int* __restrict__ dst,
                                             int* cursor, unsigned int* __restrict__ pair_buf) {
    __shared__ int hist[NBUCK];
    __shared__ int base[NBUCK];
    __shared__ int cur[NBUCK];
    int t = threadIdx.x;
    int e0 = blockIdx.x * EPB;
    for (int j = t; j < NBUCK; j += 256) { hist[j] = 0; cur[j] = 0; }
    __syncthreads();
    int d[8];
#pragma unroll
    for (int i = 0; i < 8; ++i) {
        int e = e0 + t + i * 256;
        d[i] = (e < EDGES) ? dst[e] : -1;
        if (d[i] >= 0) atomicAdd(&hist[d[i] >> BSHIFT], 1);
    }
    __syncthreads();
    for (int j = t; j < NBUCK; j += 256) {
        int h = hist[j];
        base[j] = h ? atomicAdd(&cursor[j], h) : 0;
    }
    __syncthreads();
#pragma unroll
    for (int i = 0; i < 8; ++i) {
        int e = e0 + t + i * 256;
        if (d[i] >= 0) {
            int b = d[i] >> BSHIFT;
            int rel = base[b] + atomicAdd(&cur[b], 1);
            if (rel < BSTRIDE)
                pair_buf[b * BSTRIDE + rel] = (unsigned)src[e] | ((unsigned)(d[i] & (BNODES - 1)) << 16);
        }
    }
}

// ---------------------------------------------------------------- per-bucket scatter -> node-strided CSR + deg + dinv
__global__ __launch_bounds__(256) void k_csr(const int* __restrict__ cursor, const unsigned* __restrict__ pair_buf,
                                             unsigned short* __restrict__ csr, unsigned char* __restrict__ deg8,
                                             float* __restrict__ dinv) {
    __shared__ int cur[BNODES];
    int t = threadIdx.x, b = blockIdx.x;
    if (t < BNODES) cur[t] = 0;
    __syncthreads();
    int m = cursor[b]; if (m > BSTRIDE) m = BSTRIDE;
    const unsigned* pb = pair_buf + b * BSTRIDE;
    for (int i = t; i < m; i += 256) {
        unsigned p = pb[i];
        int node = p >> 16;
        int pos = atomicAdd(&cur[node], 1);
        if (pos < DMAX)
            csr[(((b << BSHIFT) + node) << 6) + pos] = (unsigned short)(p & 0xFFFFu);
    }
    __syncthreads();
    if (t < BNODES) {
        int n = (b << BSHIFT) + t;
        if (n < NODES) {
            int c = cur[t]; if (c > DMAX) c = DMAX;
            deg8[n] = (unsigned char)c;
            dinv[n] = rsqrtf((float)(c + 1));   // + self-loop
        }
    }
}

// ---------------------------------------------------------------- GEMM1 (R11 structure, best measured 46us) -> g in BF16
__global__ __launch_bounds__(256) void k_gemm1(const float* __restrict__ x, const float* __restrict__ W1,
                                               const float* __restrict__ dinv, unsigned* __restrict__ gb) {
    __shared__ float sX[64 * 64];    // 16 KB
    int t = threadIdx.x;
    int lane = t & 63;               // node within block
    int w = t >> 6;                  // wave id 0..3
    int c0 = __builtin_amdgcn_readfirstlane(w * 16);
    int base = blockIdx.x * 64;
    int n = base + lane;

    float acc[16];
#pragma unroll
    for (int i = 0; i < 16; ++i) acc[i] = 0.f;

    for (int ch = 0; ch < 4; ++ch) {
        __syncthreads();
#pragma unroll
        for (int ii = 0; ii < 4; ++ii) {
            int i = w * 4 + ii;
            int row = 4 * i + (lane >> 4);
            int rr = base + row; if (rr >= NODES) rr = NODES - 1;
            int p = lane & 15;
            const float* gp = x + (long)rr * IND + ch * 64 + 4 * (p ^ (row & 7));
            __builtin_amdgcn_global_load_lds(
                (const __attribute__((address_space(1))) void*)(unsigned long)(const void*)gp,
                (__attribute__((address_space(3))) void*)(unsigned long)(const void*)(sX + i * 256),
                16, 0, 0);
        }
        asm volatile("s_waitcnt vmcnt(0)" ::: "memory");
        __syncthreads();

        float4 xr[16];
#pragma unroll
        for (int q = 0; q < 16; ++q)
            xr[q] = *(const float4*)&sX[(lane * 16 + (q ^ (lane & 7))) * 4];

        const float* Wb = W1 + (ch * 64) * HID + c0;
#pragma unroll
        for (int q = 0; q < 16; ++q) {
#pragma unroll
            for (int kk = 0; kk < 4; ++kk) {
                const float* wr = Wb + (q * 4 + kk) * HID;
                float xs = ((const float*)&xr[q])[kk];
#pragma unroll
                for (int ci = 0; ci < 16; ++ci)
                    acc[ci] = fmaf(xs, wr[ci], acc[ci]);
            }
        }
    }

    if (n < NODES) {
        float di = dinv[n];
        // row n: 64 bf16 = 8 uints; this thread owns uints w*4 .. w*4+3 (cols c0..c0+15)
        uint4 o;
        o.x = f2bf2(acc[0] * di,  acc[1] * di);
        o.y = f2bf2(acc[2] * di,  acc[3] * di);
        o.z = f2bf2(acc[4] * di,  acc[5] * di);
        o.w = f2bf2(acc[6] * di,  acc[7] * di);
        uint4 p;
        p.x = f2bf2(acc[8] * di,  acc[9] * di);
        p.y = f2bf2(acc[10] * di, acc[11] * di);
        p.z = f2bf2(acc[12] * di, acc[13] * di);
        p.w = f2bf2(acc[14] * di, acc[15] * di);
        uint4* go = (uint4*)(gb + (long)n * 32 + w * 8);
        go[0] = o;
        go[1] = p;
    }
}

// ---------------------------------------------------------------- conv1 gather: wave per node, 16 edges in flight, bf16 g
// lane = sub*8 + c8; lane reads uint4 #c8 of the 128B bf16 row = cols c8*8..+7
__global__ __launch_bounds__(256) void k_gather1(const unsigned short* __restrict__ csr,
                                                 const unsigned char* __restrict__ deg8,
                                                 const unsigned* __restrict__ gb, const float* __restrict__ dinv,
                                                 const float* __restrict__ b1, float* __restrict__ h1) {
    int n = (blockIdx.x * 256 + threadIdx.x) >> 6;
    int lane = threadIdx.x & 63;
    if (n >= NODES) return;
    int sub = lane >> 3;
    int c8  = lane & 7;
    const uint4* g4 = (const uint4*)gb;   // row n = g4[n*8 .. n*8+7]
    float a[8];
#pragma unroll
    for (int i = 0; i < 8; ++i) a[i] = 0.f;
    if (sub == 0) {                               // self-loop term, once
        uint4 v = g4[n * 8 + c8];
        a[0] += bf_lo(v.x); a[1] += bf_hi(v.x);
        a[2] += bf_lo(v.y); a[3] += bf_hi(v.y);
        a[4] += bf_lo(v.z); a[5] += bf_hi(v.z);
        a[6] += bf_lo(v.w); a[7] += bf_hi(v.w);
    }
    int cnt = deg8[n];
    const unsigned short* lst = csr + ((long)n << 6);
    int e = sub;
    for (; e + 8 < cnt; e += 16) {               // both e and e+8 valid for every sub
        int sA = lst[e];
        int sB = lst[e + 8];
        uint4 vA = g4[sA * 8 + c8];
        uint4 vB = g4[sB * 8 + c8];
        a[0] += bf_lo(vA.x) + bf_lo(vB.x); a[1] += bf_hi(vA.x) + bf_hi(vB.x);
        a[2] += bf_lo(vA.y) + bf_lo(vB.y); a[3] += bf_hi(vA.y) + bf_hi(vB.y);
        a[4] += bf_lo(vA.z) + bf_lo(vB.z); a[5] += bf_hi(vA.z) + bf_hi(vB.z);
        a[6] += bf_lo(vA.w) + bf_lo(vB.w); a[7] += bf_hi(vA.w) + bf_hi(vB.w);
    }
    for (; e < cnt; e += 8) {
        int s = lst[e];
        uint4 v = g4[s * 8 + c8];
        a[0] += bf_lo(v.x); a[1] += bf_hi(v.x);
        a[2] += bf_lo(v.y); a[3] += bf_hi(v.y);
        a[4] += bf_lo(v.z); a[5] += bf_hi(v.z);
        a[6] += bf_lo(v.w); a[7] += bf_hi(v.w);
    }
#pragma unroll
    for (int off = 8; off <= 32; off <<= 1) {
#pragma unroll
        for (int i = 0; i < 8; ++i) a[i] += __shfl_xor(a[i], off);
    }
    if (sub == 0) {
        float di = dinv[n];
        float4 bb0 = ((const float4*)b1)[c8 * 2];
        float4 bb1 = ((const float4*)b1)[c8 * 2 + 1];
        float4 o0, o1;
        o0.x = fmaf(a[0], di, bb0.x); o0.y = fmaf(a[1], di, bb0.y);
        o0.z = fmaf(a[2], di, bb0.z); o0.w = fmaf(a[3], di, bb0.w);
        o1.x = fmaf(a[4], di, bb1.x); o1.y = fmaf(a[5], di, bb1.y);
        o1.z = fmaf(a[6], di, bb1.z); o1.w = fmaf(a[7], di, bb1.w);
        ((float4*)h1)[n * 16 + c8 * 2] = o0;
        ((float4*)h1)[n * 16 + c8 * 2 + 1] = o1;
    }
}

// ---------------------------------------------------------------- BN stats over h1
__global__ __launch_bounds__(256) void k_bnstats(const float* __restrict__ h1, float* bnsum, float* bnsq) {
    __shared__ float sS[256], sQ[256];
    int t = threadIdx.x;
    int j = t & 63;
    int worker = (blockIdx.x * 256 + t) >> 6;
    int nworkers = (gridDim.x * 256) >> 6;
    float s = 0.f, q = 0.f;
    for (int n = worker; n < NODES; n += nworkers) {
        float v = h1[n * HID + j];
        s += v;
        q += v * v;
    }
    sS[t] = s; sQ[t] = q;
    __syncthreads();
    if (t < 64) {
        s = sS[t] + sS[t + 64] + sS[t + 128] + sS[t + 192];
        q = sQ[t] + sQ[t + 64] + sQ[t + 128] + sQ[t + 192];
        atomicAdd(&bnsum[t], s);
        atomicAdd(&bnsq[t], q);
    }
}

// ---------------------------------------------------------------- q = relu(bn(h1)) @ W2 * dinv  (bnfinal fused)
__global__ __launch_bounds__(256) void k_q(const float* __restrict__ h1, const float* __restrict__ bnsum,
                                           const float* __restrict__ bnsq, const float* __restrict__ gamma,
                                           const float* __restrict__ beta, const float* __restrict__ W2,
                                           const float* __restrict__ dinv, float* q) {
    int gt = blockIdx.x * 256 + threadIdx.x;
    int lane = threadIdx.x & 63;
    int n = gt >> 6;
    if (n >= NODES) return;
    float mean = bnsum[lane] * (1.f / NODES);
    float var  = bnsq[lane] * (1.f / NODES) - mean * mean;
    float sc = gamma[lane] * rsqrtf(var + BN_EPS);
    float sh = beta[lane] - mean * sc;
    float v = fmaxf(fmaf(h1[n * HID + lane], sc, sh), 0.f);
    float q0 = v * W2[lane * 2 + 0];
    float q1 = v * W2[lane * 2 + 1];
#pragma unroll
    for (int off = 32; off; off >>= 1) {
        q0 += __shfl_down(q0, off);
        q1 += __shfl_down(q1, off);
    }
    if (lane == 0) {
        float di = dinv[n];
        q[n * 2 + 0] = q0 * di;
        q[n * 2 + 1] = q1 * di;
    }
}

// ---------------------------------------------------------------- conv2 gather: 4 lanes per node
__global__ __launch_bounds__(256) void k_gather2(const unsigned short* __restrict__ csr,
                                                 const unsigned char* __restrict__ deg8,
                                                 const float* __restrict__ q, const float* __restrict__ dinv,
                                                 const float* __restrict__ b2, float* __restrict__ out) {
    int gt = blockIdx.x * 256 + threadIdx.x;
    int n = gt >> 2;
    int sub = gt & 3;
    if (n >= NODES) return;
    const float2* q2 = (const float2*)q;
    float q0 = 0.f, q1 = 0.f;
    if (sub == 0) { float2 s = q2[n]; q0 = s.x; q1 = s.y; }   // self-loop
    int cnt = deg8[n];
    const unsigned short* lst = csr + ((long)n << 6);
    for (int e = sub; e < cnt; e += 4) {
        float2 m = q2[lst[e]];
        q0 += m.x; q1 += m.y;
    }
    q0 += __shfl_xor(q0, 1); q1 += __shfl_xor(q1, 1);
    q0 += __shfl_xor(q0, 2); q1 += __shfl_xor(q1, 2);
    if (sub == 0) {
        float di = dinv[n];
        out[n * 2 + 0] = fmaf(q0, di, b2[0]);
        out[n * 2 + 1] = fmaf(q1, di, b2[1]);
    }
}

extern "C" void kernel_launch(void* const* d_in, const int* in_sizes, int n_in,
                              void* d_out, int out_size, void* d_ws, size_t ws_size,
                              hipStream_t stream) {
    const float* x     = (const float*)d_in[0];
    const int*   ei    = (const int*)d_in[1];
    const float* W1    = (const float*)d_in[2];
    const float* b1    = (const float*)d_in[3];
    const float* gamma = (const float*)d_in[4];
    const float* beta  = (const float*)d_in[5];
    const float* W2    = (const float*)d_in[6];
    const float* b2    = (const float*)d_in[7];
    const int* src = ei;
    const int* dst = ei + EDGES;
    float* out = (float*)d_out;

    char* base = (char*)d_ws;
    float*    dinv = (float*)base;                         base += 50048 * 4;
    unsigned* gb   = (unsigned*)base;                      base += 50048 * 32 * 4;   // bf16 g: [n][64] = 32 uints/row
    float*    h1   = (float*)base;                         base += (size_t)NODES * HID * 4;
    float*    bnsum = (float*)base;                        base += 64 * 4;
    float*    bnsq  = (float*)base;                        base += 64 * 4;
    int*      cursor = (int*)base;                         base += 1024 * 4;
    unsigned short* csr = (unsigned short*)base;           base += (size_t)50176 * 64 * 2;
    unsigned char*  deg8 = (unsigned char*)base;           base += 50176;
    unsigned* pair_buf = (unsigned*)h1;                    // aliases h1 (dead before gather1 writes h1)
    float*    q = (float*)gb;                              // aliases gb (dead after gather1)

    k_init <<<1, 1024, 0, stream>>>(cursor, bnsum, bnsq);
    k_bin  <<<BIN_BLOCKS, 256, 0, stream>>>(src, dst, cursor, pair_buf);
    k_csr  <<<NBUCK, 256, 0, stream>>>(cursor, pair_buf, csr, deg8, dinv);
    k_gemm1<<<GBLK, 256, 0, stream>>>(x, W1, dinv, gb);
    k_gather1<<<(NODES * 64) / 256, 256, 0, stream>>>(csr, deg8, gb, dinv, b1, h1);
    k_bnstats<<<256, 256, 0, stream>>>(h1, bnsum, bnsq);
    k_q<<<(NODES * 64) / 256, 256, 0, stream>>>(h1, bnsum, bnsq, gamma, beta, W2, dinv, q);
    k_gather2<<<(NODES * 4 + 255) / 256, 256, 0, stream>>>(csr, deg8, q, dinv, b2, out);
}

// Round 17
// 126.041 us; speedup vs baseline: 1.6767x; 1.1528x over previous
//
#include <hip/hip_runtime.h>
#include <hip/hip_bf16.h>

#define NODES   50000
#define EDGES   1200000
#define IND     256
#define HID     64
#define BN_EPS  1e-5f
#define BSHIFT  6
#define BNODES  64
#define NBUCK   782                 // ceil(50000/64)
#define EPB     2048
#define BIN_BLOCKS 586              // x 2048 = 1,200,128 >= EDGES
#define BSTRIDE 2560                // bucket capacity (mean 1536, +26 sigma)
#define DMAX    64                  // per-node CSR slots (max in-deg Poisson(24) ~ 55)
#define GBLK    782                 // gemm1: 64 nodes per block

using bf16x8 = __attribute__((ext_vector_type(8))) short;
using f32x4  = __attribute__((ext_vector_type(4))) float;

static __device__ __forceinline__ unsigned f2bf2(float lo, float hi) {
    __hip_bfloat16 a = __float2bfloat16(lo);
    __hip_bfloat16 b = __float2bfloat16(hi);
    unsigned ua = *reinterpret_cast<unsigned short*>(&a);
    unsigned ub = *reinterpret_cast<unsigned short*>(&b);
    return ua | (ub << 16);
}
static __device__ __forceinline__ float bf_lo(unsigned u) {
    u <<= 16; return *reinterpret_cast<float*>(&u);
}
static __device__ __forceinline__ float bf_hi(unsigned u) {
    u &= 0xFFFF0000u; return *reinterpret_cast<float*>(&u);
}

// ---------------------------------------------------------------- init
__global__ __launch_bounds__(1024) void k_init(int* cursor, float* bnsum, float* bnsq) {
    int t = threadIdx.x;
    if (t < NBUCK) cursor[t] = 0;
    if (t < HID) { bnsum[t] = 0.f; bnsq[t] = 0.f; }
}

// ---------------------------------------------------------------- W1 -> bf16 transposed [64 cols][256 k]
__global__ __launch_bounds__(256) void k_wt(const float* __restrict__ W1, unsigned short* __restrict__ W1t) {
    int id = blockIdx.x * 256 + threadIdx.x;    // 4096 = 64 c x 64 k4
    int c = id >> 6, k4 = id & 63;
    float v0 = W1[(k4 * 4 + 0) * HID + c];
    float v1 = W1[(k4 * 4 + 1) * HID + c];
    float v2 = W1[(k4 * 4 + 2) * HID + c];
    float v3 = W1[(k4 * 4 + 3) * HID + c];
    uint2 p; p.x = f2bf2(v0, v1); p.y = f2bf2(v2, v3);
    *(uint2*)&W1t[c * 256 + k4 * 4] = p;
}

// ---------------------------------------------------------------- bin edges by dst bucket (fixed-stride buckets)
__global__ __launch_bounds__(256) void k_bin(const int* __restrict__ src, const int* __restrict__ dst,
                                             int* cursor, unsigned int* __restrict__ pair_buf) {
    __shared__ int hist[NBUCK];
    __shared__ int base[NBUCK];
    __shared__ int cur[NBUCK];
    int t = threadIdx.x;
    int e0 = blockIdx.x * EPB;
    for (int j = t; j < NBUCK; j += 256) { hist[j] = 0; cur[j] = 0; }
    __syncthreads();
    int d[8];
#pragma unroll
    for (int i = 0; i < 8; ++i) {
        int e = e0 + t + i * 256;
        d[i] = (e < EDGES) ? dst[e] : -1;
        if (d[i] >= 0) atomicAdd(&hist[d[i] >> BSHIFT], 1);
    }
    __syncthreads();
    for (int j = t; j < NBUCK; j += 256) {
        int h = hist[j];
        base[j] = h ? atomicAdd(&cursor[j], h) : 0;
    }
    __syncthreads();
#pragma unroll
    for (int i = 0; i < 8; ++i) {
        int e = e0 + t + i * 256;
        if (d[i] >= 0) {
            int b = d[i] >> BSHIFT;
            int rel = base[b] + atomicAdd(&cur[b], 1);
            if (rel < BSTRIDE)
                pair_buf[b * BSTRIDE + rel] = (unsigned)src[e] | ((unsigned)(d[i] & (BNODES - 1)) << 16);
        }
    }
}

// ---------------------------------------------------------------- per-bucket scatter -> node-strided CSR + deg + dinv
__global__ __launch_bounds__(256) void k_csr(const int* __restrict__ cursor, const unsigned* __restrict__ pair_buf,
                                             unsigned short* __restrict__ csr, unsigned char* __restrict__ deg8,
                                             float* __restrict__ dinv) {
    __shared__ int cur[BNODES];
    int t = threadIdx.x, b = blockIdx.x;
    if (t < BNODES) cur[t] = 0;
    __syncthreads();
    int m = cursor[b]; if (m > BSTRIDE) m = BSTRIDE;
    const unsigned* pb = pair_buf + b * BSTRIDE;
    for (int i = t; i < m; i += 256) {
        unsigned p = pb[i];
        int node = p >> 16;
        int pos = atomicAdd(&cur[node], 1);
        if (pos < DMAX)
            csr[(((b << BSHIFT) + node) << 6) + pos] = (unsigned short)(p & 0xFFFFu);
    }
    __syncthreads();
    if (t < BNODES) {
        int n = (b << BSHIFT) + t;
        if (n < NODES) {
            int c = cur[t]; if (c > DMAX) c = DMAX;
            deg8[n] = (unsigned char)c;
            dinv[n] = rsqrtf((float)(c + 1));   // + self-loop
        }
    }
}

// ---------------------------------------------------------------- GEMM1 via MFMA bf16: g = (x @ W1) * dinv
// 64 nodes/block, 4 waves; wave w -> nodes w*16..+15 (M=16), N=64 as 4 col-tiles, K=256 as 8 chunks.
// xb: LDS bf16 [64][256], 16B-slot XOR swizzle (slot ^= row&7) -> conflict-free fragment reads.
// wt: LDS bf16 [64 cols][256 k], staged by global_load_lds with pre-swizzled GLOBAL source (G21).
__global__ __launch_bounds__(256) void k_gemm1(const float* __restrict__ x, const unsigned short* __restrict__ W1t,
                                               const float* __restrict__ dinv, unsigned short* __restrict__ gb) {
    __shared__ unsigned short xb[64 * 256];   // 32 KB
    __shared__ unsigned short wt[64 * 256];   // 32 KB
    int t = threadIdx.x, lane = t & 63, w = t >> 6;
    int base = blockIdx.x * 64;
    const float4* x4 = (const float4*)x;

    // stage xb: slot s = i*256+t -> row = s>>6 (0..63), pos = s&63 (float4 index)
#pragma unroll
    for (int i = 0; i < 16; ++i) {
        int s = i * 256 + t;
        int row = s >> 6, pos = s & 63;
        int rr = base + row; if (rr >= NODES) rr = NODES - 1;
        float4 v = x4[(long)rr * 64 + pos];
        uint2 p; p.x = f2bf2(v.x, v.y); p.y = f2bf2(v.z, v.w);
        *(uint2*)&xb[row * 256 + (((pos >> 1) ^ (row & 7)) << 3) + ((pos & 1) << 2)] = p;
    }
    // stage wt: inst j covers LDS bytes j*1024 (rows 2j, 2j+1); lane l -> row = 2j+(l>>5), slotL = l&31
    // LDS slot slotL holds global slot s = slotL ^ (row&7)
#pragma unroll
    for (int jj = 0; jj < 8; ++jj) {
        int j = w * 8 + jj;
        int row = 2 * j + (lane >> 5);
        int s = (lane & 31) ^ (row & 7);
        const unsigned short* gp = W1t + row * 256 + s * 8;
        __builtin_amdgcn_global_load_lds(
            (const __attribute__((address_space(1))) void*)(unsigned long)(const void*)gp,
            (__attribute__((address_space(3))) void*)(unsigned long)(const void*)(wt + j * 512),
            16, 0, 0);
    }
    asm volatile("s_waitcnt vmcnt(0)" ::: "memory");
    __syncthreads();

    int r = lane & 15, hi = lane >> 4;   // A row / D col = r; k-group = hi
    f32x4 acc[4];
#pragma unroll
    for (int ct = 0; ct < 4; ++ct) acc[ct] = f32x4{0.f, 0.f, 0.f, 0.f};

    int m0 = w * 16;
#pragma unroll
    for (int kc = 0; kc < 8; ++kc) {
        bf16x8 a = *(const bf16x8*)&xb[(m0 + r) * 256 + (((kc * 4 + hi) ^ (r & 7)) << 3)];
#pragma unroll
        for (int ct = 0; ct < 4; ++ct) {
            int c = ct * 16 + r;
            bf16x8 b = *(const bf16x8*)&wt[c * 256 + (((kc * 4 + hi) ^ (c & 7)) << 3)];
            acc[ct] = __builtin_amdgcn_mfma_f32_16x16x32_bf16(a, b, acc[ct], 0, 0, 0);
        }
    }

    // D: col = r, row = hi*4 + reg  (HW-verified C/D layout)
#pragma unroll
    for (int reg = 0; reg < 4; ++reg) {
        int nd = base + m0 + hi * 4 + reg;
        if (nd < NODES) {
            float di = dinv[nd];
#pragma unroll
            for (int ct = 0; ct < 4; ++ct) {
                __hip_bfloat16 hv = __float2bfloat16(acc[ct][reg] * di);
                gb[(long)nd * 64 + ct * 16 + r] = *reinterpret_cast<unsigned short*>(&hv);
            }
        }
    }
}

// ---------------------------------------------------------------- conv1 gather: wave per node, 16 edges in flight, bf16 g
__global__ __launch_bounds__(256) void k_gather1(const unsigned short* __restrict__ csr,
                                                 const unsigned char* __restrict__ deg8,
                                                 const unsigned* __restrict__ gb, const float* __restrict__ dinv,
                                                 const float* __restrict__ b1, float* __restrict__ h1) {
    int n = (blockIdx.x * 256 + threadIdx.x) >> 6;
    int lane = threadIdx.x & 63;
    if (n >= NODES) return;
    int sub = lane >> 3;
    int c8  = lane & 7;
    const uint4* g4 = (const uint4*)gb;   // row n = g4[n*8 .. n*8+7]
    float a[8];
#pragma unroll
    for (int i = 0; i < 8; ++i) a[i] = 0.f;
    if (sub == 0) {                               // self-loop term, once
        uint4 v = g4[n * 8 + c8];
        a[0] += bf_lo(v.x); a[1] += bf_hi(v.x);
        a[2] += bf_lo(v.y); a[3] += bf_hi(v.y);
        a[4] += bf_lo(v.z); a[5] += bf_hi(v.z);
        a[6] += bf_lo(v.w); a[7] += bf_hi(v.w);
    }
    int cnt = deg8[n];
    const unsigned short* lst = csr + ((long)n << 6);
    int e = sub;
    for (; e + 8 < cnt; e += 16) {
        int sA = lst[e];
        int sB = lst[e + 8];
        uint4 vA = g4[sA * 8 + c8];
        uint4 vB = g4[sB * 8 + c8];
        a[0] += bf_lo(vA.x) + bf_lo(vB.x); a[1] += bf_hi(vA.x) + bf_hi(vB.x);
        a[2] += bf_lo(vA.y) + bf_lo(vB.y); a[3] += bf_hi(vA.y) + bf_hi(vB.y);
        a[4] += bf_lo(vA.z) + bf_lo(vB.z); a[5] += bf_hi(vA.z) + bf_hi(vB.z);
        a[6] += bf_lo(vA.w) + bf_lo(vB.w); a[7] += bf_hi(vA.w) + bf_hi(vB.w);
    }
    for (; e < cnt; e += 8) {
        int s = lst[e];
        uint4 v = g4[s * 8 + c8];
        a[0] += bf_lo(v.x); a[1] += bf_hi(v.x);
        a[2] += bf_lo(v.y); a[3] += bf_hi(v.y);
        a[4] += bf_lo(v.z); a[5] += bf_hi(v.z);
        a[6] += bf_lo(v.w); a[7] += bf_hi(v.w);
    }
#pragma unroll
    for (int off = 8; off <= 32; off <<= 1) {
#pragma unroll
        for (int i = 0; i < 8; ++i) a[i] += __shfl_xor(a[i], off);
    }
    if (sub == 0) {
        float di = dinv[n];
        float4 bb0 = ((const float4*)b1)[c8 * 2];
        float4 bb1 = ((const float4*)b1)[c8 * 2 + 1];
        float4 o0, o1;
        o0.x = fmaf(a[0], di, bb0.x); o0.y = fmaf(a[1], di, bb0.y);
        o0.z = fmaf(a[2], di, bb0.z); o0.w = fmaf(a[3], di, bb0.w);
        o1.x = fmaf(a[4], di, bb1.x); o1.y = fmaf(a[5], di, bb1.y);
        o1.z = fmaf(a[6], di, bb1.z); o1.w = fmaf(a[7], di, bb1.w);
        ((float4*)h1)[n * 16 + c8 * 2] = o0;
        ((float4*)h1)[n * 16 + c8 * 2 + 1] = o1;
    }
}

// ---------------------------------------------------------------- BN stats over h1
__global__ __launch_bounds__(256) void k_bnstats(const float* __restrict__ h1, float* bnsum, float* bnsq) {
    __shared__ float sS[256], sQ[256];
    int t = threadIdx.x;
    int j = t & 63;
    int worker = (blockIdx.x * 256 + t) >> 6;
    int nworkers = (gridDim.x * 256) >> 6;
    float s = 0.f, q = 0.f;
    for (int n = worker; n < NODES; n += nworkers) {
        float v = h1[n * HID + j];
        s += v;
        q += v * v;
    }
    sS[t] = s; sQ[t] = q;
    __syncthreads();
    if (t < 64) {
        s = sS[t] + sS[t + 64] + sS[t + 128] + sS[t + 192];
        q = sQ[t] + sQ[t + 64] + sQ[t + 128] + sQ[t + 192];
        atomicAdd(&bnsum[t], s);
        atomicAdd(&bnsq[t], q);
    }
}

// ---------------------------------------------------------------- q = relu(bn(h1)) @ W2 * dinv  (bnfinal fused)
__global__ __launch_bounds__(256) void k_q(const float* __restrict__ h1, const float* __restrict__ bnsum,
                                           const float* __restrict__ bnsq, const float* __restrict__ gamma,
                                           const float* __restrict__ beta, const float* __restrict__ W2,
                                           const float* __restrict__ dinv, float* q) {
    int gt = blockIdx.x * 256 + threadIdx.x;
    int lane = threadIdx.x & 63;
    int n = gt >> 6;
    if (n >= NODES) return;
    float mean = bnsum[lane] * (1.f / NODES);
    float var  = bnsq[lane] * (1.f / NODES) - mean * mean;
    float sc = gamma[lane] * rsqrtf(var + BN_EPS);
    float sh = beta[lane] - mean * sc;
    float v = fmaxf(fmaf(h1[n * HID + lane], sc, sh), 0.f);
    float q0 = v * W2[lane * 2 + 0];
    float q1 = v * W2[lane * 2 + 1];
#pragma unroll
    for (int off = 32; off; off >>= 1) {
        q0 += __shfl_down(q0, off);
        q1 += __shfl_down(q1, off);
    }
    if (lane == 0) {
        float di = dinv[n];
        q[n * 2 + 0] = q0 * di;
        q[n * 2 + 1] = q1 * di;
    }
}

// ---------------------------------------------------------------- conv2 gather: 4 lanes per node
__global__ __launch_bounds__(256) void k_gather2(const unsigned short* __restrict__ csr,
                                                 const unsigned char* __restrict__ deg8,
                                                 const float* __restrict__ q, const float* __restrict__ dinv,
                                                 const float* __restrict__ b2, float* __restrict__ out) {
    int gt = blockIdx.x * 256 + threadIdx.x;
    int n = gt >> 2;
    int sub = gt & 3;
    if (n >= NODES) return;
    const float2* q2 = (const float2*)q;
    float q0 = 0.f, q1 = 0.f;
    if (sub == 0) { float2 s = q2[n]; q0 = s.x; q1 = s.y; }   // self-loop
    int cnt = deg8[n];
    const unsigned short* lst = csr + ((long)n << 6);
    for (int e = sub; e < cnt; e += 4) {
        float2 m = q2[lst[e]];
        q0 += m.x; q1 += m.y;
    }
    q0 += __shfl_xor(q0, 1); q1 += __shfl_xor(q1, 1);
    q0 += __shfl_xor(q0, 2); q1 += __shfl_xor(q1, 2);
    if (sub == 0) {
        float di = dinv[n];
        out[n * 2 + 0] = fmaf(q0, di, b2[0]);
        out[n * 2 + 1] = fmaf(q1, di, b2[1]);
    }
}

extern "C" void kernel_launch(void* const* d_in, const int* in_sizes, int n_in,
                              void* d_out, int out_size, void* d_ws, size_t ws_size,
                              hipStream_t stream) {
    const float* x     = (const float*)d_in[0];
    const int*   ei    = (const int*)d_in[1];
    const float* W1    = (const float*)d_in[2];
    const float* b1    = (const float*)d_in[3];
    const float* gamma = (const float*)d_in[4];
    const float* beta  = (const float*)d_in[5];
    const float* W2    = (const float*)d_in[6];
    const float* b2    = (const float*)d_in[7];
    const int* src = ei;
    const int* dst = ei + EDGES;
    float* out = (float*)d_out;

    char* base = (char*)d_ws;
    float*    dinv = (float*)base;                         base += 50048 * 4;
    unsigned short* gb = (unsigned short*)base;            base += (size_t)50048 * 64 * 2;  // bf16 g [n][64]
    float*    h1   = (float*)base;                         base += (size_t)NODES * HID * 4;
    float*    bnsum = (float*)base;                        base += 64 * 4;
    float*    bnsq  = (float*)base;                        base += 64 * 4;
    int*      cursor = (int*)base;                         base += 1024 * 4;
    unsigned short* csr = (unsigned short*)base;           base += (size_t)50176 * 64 * 2;
    unsigned char*  deg8 = (unsigned char*)base;           base += 50176;
    unsigned short* W1t = (unsigned short*)base;           base += (size_t)64 * 256 * 2;
    unsigned* pair_buf = (unsigned*)h1;                    // aliases h1 (dead before gather1 writes h1)
    float*    q = (float*)gb;                              // aliases gb (dead after gather1)

    k_init <<<1, 1024, 0, stream>>>(cursor, bnsum, bnsq);
    k_bin  <<<BIN_BLOCKS, 256, 0, stream>>>(src, dst, cursor, pair_buf);
    k_csr  <<<NBUCK, 256, 0, stream>>>(cursor, pair_buf, csr, deg8, dinv);
    k_wt   <<<16, 256, 0, stream>>>(W1, W1t);
    k_gemm1<<<GBLK, 256, 0, stream>>>(x, W1t, dinv, gb);
    k_gather1<<<(NODES * 64) / 256, 256, 0, stream>>>(csr, deg8, (const unsigned*)gb, dinv, b1, h1);
    k_bnstats<<<256, 256, 0, stream>>>(h1, bnsum, bnsq);
    k_q<<<(NODES * 64) / 256, 256, 0, stream>>>(h1, bnsum, bnsq, gamma, beta, W2, dinv, q);
    k_gather2<<<(NODES * 4 + 255) / 256, 256, 0, stream>>>(csr, deg8, q, dinv, b2, out);
}

// Round 18
// 117.405 us; speedup vs baseline: 1.8001x; 1.0736x over previous
//
#include <hip/hip_runtime.h>
#include <hip/hip_bf16.h>

#define NODES   50000
#define EDGES   1200000
#define IND     256
#define HID     64
#define BN_EPS  1e-5f
#define BSHIFT  6
#define BNODES  64
#define NBUCK   782                 // ceil(50000/64)
#define EPB     4096
#define BIN_BLOCKS 293              // x 4096 = 1,200,128 >= EDGES
#define BSTRIDE 2560                // bucket capacity (mean 1536, +26 sigma)
#define DMAX    64                  // per-node CSR slots (max in-deg Poisson(24) ~ 55)
#define GBLK    782                 // gemm1: 64 nodes per block

using bf16x8 = __attribute__((ext_vector_type(8))) short;
using f32x4  = __attribute__((ext_vector_type(4))) float;

static __device__ __forceinline__ unsigned f2bf2(float lo, float hi) {
    __hip_bfloat16 a = __float2bfloat16(lo);
    __hip_bfloat16 b = __float2bfloat16(hi);
    unsigned ua = *reinterpret_cast<unsigned short*>(&a);
    unsigned ub = *reinterpret_cast<unsigned short*>(&b);
    return ua | (ub << 16);
}
static __device__ __forceinline__ float bf_lo(unsigned u) {
    u <<= 16; return *reinterpret_cast<float*>(&u);
}
static __device__ __forceinline__ float bf_hi(unsigned u) {
    u &= 0xFFFF0000u; return *reinterpret_cast<float*>(&u);
}

// ---------------------------------------------------------------- prep: W1->bf16^T (blocks 0..15) + init (block 16)
__global__ __launch_bounds__(256) void k_prep(const float* __restrict__ W1, unsigned short* __restrict__ W1t,
                                              int* cursor, float* bnsum, float* bnsq) {
    int t = threadIdx.x;
    if (blockIdx.x < 16) {
        int id = blockIdx.x * 256 + t;          // 4096 = 64 c x 64 k4
        int c = id >> 6, k4 = id & 63;
        float v0 = W1[(k4 * 4 + 0) * HID + c];
        float v1 = W1[(k4 * 4 + 1) * HID + c];
        float v2 = W1[(k4 * 4 + 2) * HID + c];
        float v3 = W1[(k4 * 4 + 3) * HID + c];
        uint2 p; p.x = f2bf2(v0, v1); p.y = f2bf2(v2, v3);
        *(uint2*)&W1t[c * 256 + k4 * 4] = p;
    } else {
        for (int j = t; j < NBUCK; j += 256) cursor[j] = 0;
        if (t < HID) { bnsum[t] = 0.f; bnsq[t] = 0.f; }
    }
}

// ---------------------------------------------------------------- bin edges by dst bucket (fixed-stride buckets)
__global__ __launch_bounds__(256) void k_bin(const int* __restrict__ src, const int* __restrict__ dst,
                                             int* cursor, unsigned int* __restrict__ pair_buf) {
    __shared__ int hist[NBUCK];
    __shared__ int base[NBUCK];
    __shared__ int cur[NBUCK];
    int t = threadIdx.x;
    int e0 = blockIdx.x * EPB;
    for (int j = t; j < NBUCK; j += 256) { hist[j] = 0; cur[j] = 0; }
    __syncthreads();
    int d[16];
#pragma unroll
    for (int i = 0; i < 16; ++i) {
        int e = e0 + t + i * 256;
        d[i] = (e < EDGES) ? dst[e] : -1;
        if (d[i] >= 0) atomicAdd(&hist[d[i] >> BSHIFT], 1);
    }
    __syncthreads();
    for (int j = t; j < NBUCK; j += 256) {
        int h = hist[j];
        base[j] = h ? atomicAdd(&cursor[j], h) : 0;
    }
    __syncthreads();
#pragma unroll
    for (int i = 0; i < 16; ++i) {
        int e = e0 + t + i * 256;
        if (d[i] >= 0) {
            int b = d[i] >> BSHIFT;
            int rel = base[b] + atomicAdd(&cur[b], 1);
            if (rel < BSTRIDE)
                pair_buf[b * BSTRIDE + rel] = (unsigned)src[e] | ((unsigned)(d[i] & (BNODES - 1)) << 16);
        }
    }
}

// ---------------------------------------------------------------- per-bucket scatter -> node-strided CSR + deg + dinv
__global__ __launch_bounds__(256) void k_csr(const int* __restrict__ cursor, const unsigned* __restrict__ pair_buf,
                                             unsigned short* __restrict__ csr, unsigned char* __restrict__ deg8,
                                             float* __restrict__ dinv) {
    __shared__ int cur[BNODES];
    int t = threadIdx.x, b = blockIdx.x;
    if (t < BNODES) cur[t] = 0;
    __syncthreads();
    int m = cursor[b]; if (m > BSTRIDE) m = BSTRIDE;
    const unsigned* pb = pair_buf + b * BSTRIDE;
    for (int i = t; i < m; i += 256) {
        unsigned p = pb[i];
        int node = p >> 16;
        int pos = atomicAdd(&cur[node], 1);
        if (pos < DMAX)
            csr[(((b << BSHIFT) + node) << 6) + pos] = (unsigned short)(p & 0xFFFFu);
    }
    __syncthreads();
    if (t < BNODES) {
        int n = (b << BSHIFT) + t;
        if (n < NODES) {
            int c = cur[t]; if (c > DMAX) c = DMAX;
            deg8[n] = (unsigned char)c;
            dinv[n] = rsqrtf((float)(c + 1));   // + self-loop
        }
    }
}

// ---------------------------------------------------------------- GEMM1 via MFMA bf16 (R17, verified)
__global__ __launch_bounds__(256) void k_gemm1(const float* __restrict__ x, const unsigned short* __restrict__ W1t,
                                               const float* __restrict__ dinv, unsigned short* __restrict__ gb) {
    __shared__ unsigned short xb[64 * 256];   // 32 KB
    __shared__ unsigned short wt[64 * 256];   // 32 KB
    int t = threadIdx.x, lane = t & 63, w = t >> 6;
    int base = blockIdx.x * 64;
    const float4* x4 = (const float4*)x;

#pragma unroll
    for (int i = 0; i < 16; ++i) {
        int s = i * 256 + t;
        int row = s >> 6, pos = s & 63;
        int rr = base + row; if (rr >= NODES) rr = NODES - 1;
        float4 v = x4[(long)rr * 64 + pos];
        uint2 p; p.x = f2bf2(v.x, v.y); p.y = f2bf2(v.z, v.w);
        *(uint2*)&xb[row * 256 + (((pos >> 1) ^ (row & 7)) << 3) + ((pos & 1) << 2)] = p;
    }
#pragma unroll
    for (int jj = 0; jj < 8; ++jj) {
        int j = w * 8 + jj;
        int row = 2 * j + (lane >> 5);
        int s = (lane & 31) ^ (row & 7);
        const unsigned short* gp = W1t + row * 256 + s * 8;
        __builtin_amdgcn_global_load_lds(
            (const __attribute__((address_space(1))) void*)(unsigned long)(const void*)gp,
            (__attribute__((address_space(3))) void*)(unsigned long)(const void*)(wt + j * 512),
            16, 0, 0);
    }
    asm volatile("s_waitcnt vmcnt(0)" ::: "memory");
    __syncthreads();

    int r = lane & 15, hi = lane >> 4;
    f32x4 acc[4];
#pragma unroll
    for (int ct = 0; ct < 4; ++ct) acc[ct] = f32x4{0.f, 0.f, 0.f, 0.f};

    int m0 = w * 16;
#pragma unroll
    for (int kc = 0; kc < 8; ++kc) {
        bf16x8 a = *(const bf16x8*)&xb[(m0 + r) * 256 + (((kc * 4 + hi) ^ (r & 7)) << 3)];
#pragma unroll
        for (int ct = 0; ct < 4; ++ct) {
            int c = ct * 16 + r;
            bf16x8 b = *(const bf16x8*)&wt[c * 256 + (((kc * 4 + hi) ^ (c & 7)) << 3)];
            acc[ct] = __builtin_amdgcn_mfma_f32_16x16x32_bf16(a, b, acc[ct], 0, 0, 0);
        }
    }

#pragma unroll
    for (int reg = 0; reg < 4; ++reg) {
        int nd = base + m0 + hi * 4 + reg;
        if (nd < NODES) {
            float di = dinv[nd];
#pragma unroll
            for (int ct = 0; ct < 4; ++ct) {
                __hip_bfloat16 hv = __float2bfloat16(acc[ct][reg] * di);
                gb[(long)nd * 64 + ct * 16 + r] = *reinterpret_cast<unsigned short*>(&hv);
            }
        }
    }
}

// ---------------------------------------------------------------- conv1 gather: wave per node, 16 edges in flight, bf16 g
__global__ __launch_bounds__(256) void k_gather1(const unsigned short* __restrict__ csr,
                                                 const unsigned char* __restrict__ deg8,
                                                 const unsigned* __restrict__ gb, const float* __restrict__ dinv,
                                                 const float* __restrict__ b1, float* __restrict__ h1) {
    int n = (blockIdx.x * 256 + threadIdx.x) >> 6;
    int lane = threadIdx.x & 63;
    if (n >= NODES) return;
    int sub = lane >> 3;
    int c8  = lane & 7;
    const uint4* g4 = (const uint4*)gb;
    float a[8];
#pragma unroll
    for (int i = 0; i < 8; ++i) a[i] = 0.f;
    if (sub == 0) {                               // self-loop term, once
        uint4 v = g4[n * 8 + c8];
        a[0] += bf_lo(v.x); a[1] += bf_hi(v.x);
        a[2] += bf_lo(v.y); a[3] += bf_hi(v.y);
        a[4] += bf_lo(v.z); a[5] += bf_hi(v.z);
        a[6] += bf_lo(v.w); a[7] += bf_hi(v.w);
    }
    int cnt = deg8[n];
    const unsigned short* lst = csr + ((long)n << 6);
    int e = sub;
    for (; e + 8 < cnt; e += 16) {
        int sA = lst[e];
        int sB = lst[e + 8];
        uint4 vA = g4[sA * 8 + c8];
        uint4 vB = g4[sB * 8 + c8];
        a[0] += bf_lo(vA.x) + bf_lo(vB.x); a[1] += bf_hi(vA.x) + bf_hi(vB.x);
        a[2] += bf_lo(vA.y) + bf_lo(vB.y); a[3] += bf_hi(vA.y) + bf_hi(vB.y);
        a[4] += bf_lo(vA.z) + bf_lo(vB.z); a[5] += bf_hi(vA.z) + bf_hi(vB.z);
        a[6] += bf_lo(vA.w) + bf_lo(vB.w); a[7] += bf_hi(vA.w) + bf_hi(vB.w);
    }
    for (; e < cnt; e += 8) {
        int s = lst[e];
        uint4 v = g4[s * 8 + c8];
        a[0] += bf_lo(v.x); a[1] += bf_hi(v.x);
        a[2] += bf_lo(v.y); a[3] += bf_hi(v.y);
        a[4] += bf_lo(v.z); a[5] += bf_hi(v.z);
        a[6] += bf_lo(v.w); a[7] += bf_hi(v.w);
    }
#pragma unroll
    for (int off = 8; off <= 32; off <<= 1) {
#pragma unroll
        for (int i = 0; i < 8; ++i) a[i] += __shfl_xor(a[i], off);
    }
    if (sub == 0) {
        float di = dinv[n];
        float4 bb0 = ((const float4*)b1)[c8 * 2];
        float4 bb1 = ((const float4*)b1)[c8 * 2 + 1];
        float4 o0, o1;
        o0.x = fmaf(a[0], di, bb0.x); o0.y = fmaf(a[1], di, bb0.y);
        o0.z = fmaf(a[2], di, bb0.z); o0.w = fmaf(a[3], di, bb0.w);
        o1.x = fmaf(a[4], di, bb1.x); o1.y = fmaf(a[5], di, bb1.y);
        o1.z = fmaf(a[6], di, bb1.z); o1.w = fmaf(a[7], di, bb1.w);
        ((float4*)h1)[n * 16 + c8 * 2] = o0;
        ((float4*)h1)[n * 16 + c8 * 2 + 1] = o1;
    }
}

// ---------------------------------------------------------------- BN stats over h1
__global__ __launch_bounds__(256) void k_bnstats(const float* __restrict__ h1, float* bnsum, float* bnsq) {
    __shared__ float sS[256], sQ[256];
    int t = threadIdx.x;
    int j = t & 63;
    int worker = (blockIdx.x * 256 + t) >> 6;
    int nworkers = (gridDim.x * 256) >> 6;
    float s = 0.f, q = 0.f;
    for (int n = worker; n < NODES; n += nworkers) {
        float v = h1[n * HID + j];
        s += v;
        q += v * v;
    }
    sS[t] = s; sQ[t] = q;
    __syncthreads();
    if (t < 64) {
        s = sS[t] + sS[t + 64] + sS[t + 128] + sS[t + 192];
        q = sQ[t] + sQ[t + 64] + sQ[t + 128] + sQ[t + 192];
        atomicAdd(&bnsum[t], s);
        atomicAdd(&bnsq[t], q);
    }
}

// ---------------------------------------------------------------- q = relu(bn(h1)) @ W2 * dinv  (bnfinal fused)
__global__ __launch_bounds__(256) void k_q(const float* __restrict__ h1, const float* __restrict__ bnsum,
                                           const float* __restrict__ bnsq, const float* __restrict__ gamma,
                                           const float* __restrict__ beta, const float* __restrict__ W2,
                                           const float* __restrict__ dinv, float* q) {
    int gt = blockIdx.x * 256 + threadIdx.x;
    int lane = threadIdx.x & 63;
    int n = gt >> 6;
    if (n >= NODES) return;
    float mean = bnsum[lane] * (1.f / NODES);
    float var  = bnsq[lane] * (1.f / NODES) - mean * mean;
    float sc = gamma[lane] * rsqrtf(var + BN_EPS);
    float sh = beta[lane] - mean * sc;
    float v = fmaxf(fmaf(h1[n * HID + lane], sc, sh), 0.f);
    float q0 = v * W2[lane * 2 + 0];
    float q1 = v * W2[lane * 2 + 1];
#pragma unroll
    for (int off = 32; off; off >>= 1) {
        q0 += __shfl_down(q0, off);
        q1 += __shfl_down(q1, off);
    }
    if (lane == 0) {
        float di = dinv[n];
        q[n * 2 + 0] = q0 * di;
        q[n * 2 + 1] = q1 * di;
    }
}

// ---------------------------------------------------------------- conv2 gather: 4 lanes per node, 2-deep unroll
__global__ __launch_bounds__(256) void k_gather2(const unsigned short* __restrict__ csr,
                                                 const unsigned char* __restrict__ deg8,
                                                 const float* __restrict__ q, const float* __restrict__ dinv,
                                                 const float* __restrict__ b2, float* __restrict__ out) {
    int gt = blockIdx.x * 256 + threadIdx.x;
    int n = gt >> 2;
    int sub = gt & 3;
    if (n >= NODES) return;
    const float2* q2 = (const float2*)q;
    float q0 = 0.f, q1 = 0.f;
    if (sub == 0) { float2 s = q2[n]; q0 = s.x; q1 = s.y; }   // self-loop
    int cnt = deg8[n];
    const unsigned short* lst = csr + ((long)n << 6);
    int e = sub;
    for (; e + 4 < cnt; e += 8) {
        float2 mA = q2[lst[e]];
        float2 mB = q2[lst[e + 4]];
        q0 += mA.x + mB.x; q1 += mA.y + mB.y;
    }
    for (; e < cnt; e += 4) {
        float2 m = q2[lst[e]];
        q0 += m.x; q1 += m.y;
    }
    q0 += __shfl_xor(q0, 1); q1 += __shfl_xor(q1, 1);
    q0 += __shfl_xor(q0, 2); q1 += __shfl_xor(q1, 2);
    if (sub == 0) {
        float di = dinv[n];
        out[n * 2 + 0] = fmaf(q0, di, b2[0]);
        out[n * 2 + 1] = fmaf(q1, di, b2[1]);
    }
}

extern "C" void kernel_launch(void* const* d_in, const int* in_sizes, int n_in,
                              void* d_out, int out_size, void* d_ws, size_t ws_size,
                              hipStream_t stream) {
    const float* x     = (const float*)d_in[0];
    const int*   ei    = (const int*)d_in[1];
    const float* W1    = (const float*)d_in[2];
    const float* b1    = (const float*)d_in[3];
    const float* gamma = (const float*)d_in[4];
    const float* beta  = (const float*)d_in[5];
    const float* W2    = (const float*)d_in[6];
    const float* b2    = (const float*)d_in[7];
    const int* src = ei;
    const int* dst = ei + EDGES;
    float* out = (float*)d_out;

    char* base = (char*)d_ws;
    float*    dinv = (float*)base;                         base += 50048 * 4;
    unsigned short* gb = (unsigned short*)base;            base += (size_t)50048 * 64 * 2;  // bf16 g [n][64]
    float*    h1   = (float*)base;                         base += (size_t)NODES * HID * 4;
    float*    bnsum = (float*)base;                        base += 64 * 4;
    float*    bnsq  = (float*)base;                        base += 64 * 4;
    int*      cursor = (int*)base;                         base += 1024 * 4;
    unsigned short* csr = (unsigned short*)base;           base += (size_t)50176 * 64 * 2;
    unsigned char*  deg8 = (unsigned char*)base;           base += 50176;
    unsigned short* W1t = (unsigned short*)base;           base += (size_t)64 * 256 * 2;
    unsigned* pair_buf = (unsigned*)h1;                    // aliases h1 (dead before gather1 writes h1)
    float*    q = (float*)gb;                              // aliases gb (dead after gather1)

    k_prep <<<17, 256, 0, stream>>>(W1, W1t, cursor, bnsum, bnsq);
    k_bin  <<<BIN_BLOCKS, 256, 0, stream>>>(src, dst, cursor, pair_buf);
    k_csr  <<<NBUCK, 256, 0, stream>>>(cursor, pair_buf, csr, deg8, dinv);
    k_gemm1<<<GBLK, 256, 0, stream>>>(x, W1t, dinv, gb);
    k_gather1<<<(NODES * 64) / 256, 256, 0, stream>>>(csr, deg8, (const unsigned*)gb, dinv, b1, h1);
    k_bnstats<<<256, 256, 0, stream>>>(h1, bnsum, bnsq);
    k_q<<<(NODES * 64) / 256, 256, 0, stream>>>(h1, bnsum, bnsq, gamma, beta, W2, dinv, q);
    k_gather2<<<(NODES * 4 + 255) / 256, 256, 0, stream>>>(csr, deg8, q, dinv, b2, out);
}